// Round 13
// baseline (126.688 us; speedup 1.0000x reference)
//
#include <hip/hip_runtime.h>
#include <math.h>

#ifndef __has_builtin
#define __has_builtin(x) 0
#endif

#define NPTS   131072
#define FCH    16
#define CSND   343.0f
#define PB     16           // points per pass
#define BLOCK  256          // 4 waves
#define GRID   768          // 3 WG/CU * 256 CUs, persistent
#define NBLK   (NPTS / PB)  // 8192

typedef _Float16 half8 __attribute__((ext_vector_type(8)));
typedef _Float16 h2 __attribute__((ext_vector_type(2)));
typedef float    f32x4 __attribute__((ext_vector_type(4)));

static __device__ __forceinline__ h2 ph2(float a, float b) {
#if __has_builtin(__builtin_amdgcn_cvt_pkrtz)
  return __builtin_bit_cast(h2, __builtin_amdgcn_cvt_pkrtz(a, b));
#else
  h2 v; v[0] = (_Float16)a; v[1] = (_Float16)b;
  return v;
#endif
}
static __device__ __forceinline__ unsigned bc(h2 v) {
  return __builtin_bit_cast(unsigned, v);
}

// tanh(x) = 1 - 2/(e^{2x}+1): 5 VALU ops, monotone-correct at +/-inf.
static __device__ __forceinline__ float mytanh(float x) {
#if __has_builtin(__builtin_amdgcn_exp2f)
  float e = __builtin_amdgcn_exp2f(2.885390082f * x);   // 2*log2(e)*x
#else
  float e = __expf(2.0f * x);
#endif
  return fmaf(-2.0f, __builtin_amdgcn_rcpf(e + 1.0f), 1.0f);
}

// r12 kernel with s_HG single-buffered: 48 KB LDS -> 3 WG/CU (launch_bounds(256,3)).
//   s_A[2][80][64] dw : A f16, rows v*16+p, chunk c (8 units) at (c ^ p)
//   s_HG[16][128] dw  : point p row; dword q=16w+col holds the (j, j+16) pair
//     with j = 32*(q>>4) + (q&15); h2-pair at swizzled pos, G-pair at pos+64.
//     w3f k-rows permuted identically: kap -> j = 32*(q>>4)+16*(kap&1)+(q&15).
// Per-pass schedule (TWO barriers, overlap preserved):
//   [waves 0,1: D(i-1) reads HG | all: A(i+1)->s_A[par^1] || B(i) reads s_A[par]]
//   b1  [C(i) -> HG]  b2
// Hazards: D(i-1) rd HG vs C(i) wr -> spans b1(i); D(i) rd (next iter, pre-b1)
//   vs C(i) wr -> spans b2(i); A(i+1) wr s_A[p^1] vs B(i-1) rd -> spans
//   b1(i-1)+b2(i-1); B(i) rd s_A[p] vs A(i) wr (iter i-1) -> spans b1/b2(i-1).

__global__ __launch_bounds__(BLOCK, 3) void helmholtz_kernel(
    const float* __restrict__ x,      // [N,3]
    const float* __restrict__ omega,  // [16]
    const float* __restrict__ W1,     // [3,128]
    const float* __restrict__ b1,     // [128]
    const float* __restrict__ W2,     // [128,128]
    const float* __restrict__ b2,     // [128]
    const float* __restrict__ W3,     // [128,32]
    const float* __restrict__ b3,     // [32]
    float* __restrict__ out)
{
  __shared__ unsigned s_A[2][80 * 64];  // 40 KB
  __shared__ unsigned s_HG[16 * 128];   //  8 KB

  const int tid  = threadIdx.x;
  const int w    = tid >> 6;   // wave 0..3
  const int l    = tid & 63;
  const int col  = l & 15;
  const int quad = l >> 4;
  const int nh   = w & 1;      // D: 0 = real cols, 1 = imag cols

  // ---- phase A: point pA = tid>>4, unit pairs (8g+2u2, 8g+2u2+1), packed f16 ----
  const int pA = tid >> 4;
  const int g  = tid & 15;
  h2 wx2[4], wy2[4], wz2[4], bB2[4], m2wq2[4];
#pragma unroll
  for (int u2 = 0; u2 < 4; u2++) {
    int u0 = 8 * g + 2 * u2, u1 = u0 + 1;
    float ax = W1[u0], ay = W1[128 + u0], az = W1[256 + u0];
    float bx = W1[u1], by = W1[128 + u1], bz = W1[256 + u1];
    wx2[u2] = ph2(ax, bx); wy2[u2] = ph2(ay, by); wz2[u2] = ph2(az, bz);
    bB2[u2] = ph2(b1[u0], b1[u1]);
    m2wq2[u2] = ph2(-2.0f * (ax * ax + ay * ay + az * az),
                    -2.0f * (bx * bx + by * by + bz * bz));
  }

  // ---- W2^T fragments: n-tiles 2w, 2w+1 (32 VGPRs) ----
  half8 w2f[2][4];
#pragma unroll
  for (int ntl = 0; ntl < 2; ntl++) {
    const int n = 32 * w + 16 * ntl + col;
#pragma unroll
    for (int ks = 0; ks < 4; ks++) {
      half8 f;
#pragma unroll
      for (int j8 = 0; j8 < 8; j8++)
        f[j8] = (_Float16)W2[(ks * 32 + (quad << 3) + j8) * 128 + n];
      w2f[ntl][ks] = f;
    }
  }
  // ---- W3^T fragment, k-permuted to match paired HG layout (16 VGPRs) ----
  half8 w3f[4];
#pragma unroll
  for (int ks = 0; ks < 4; ks++) {
    half8 f;
#pragma unroll
    for (int j8 = 0; j8 < 8; j8++) {
      int kap = ks * 32 + (quad << 3) + j8;
      int q   = kap >> 1;
      int j   = 32 * (q >> 4) + 16 * (kap & 1) + (q & 15);
      f[j8] = (_Float16)W3[j * 32 + 16 * nh + col];
    }
    w3f[ks] = f;
  }

  const float b2r0 = b2[32 * w + col];
  const float b2r1 = b2[32 * w + 16 + col];
  float k2v = 0.0f;
  if (col >= 1) {
    float om = omega[col] * (1.0f / CSND);
    k2v = om * om;
  }
  const float b3v = b3[16 * nh + col];
  const h2 one2 = {(_Float16)1.0f, (_Float16)1.0f};
  const h2 m2c  = {(_Float16)-2.0f, (_Float16)-2.0f};

  float wsum = 0.0f;

  // ---- phase A: packed f16, 5 ds_write_b128 ----
  auto phaseA = [&](int blk, int buf) {
    const float* xp = x + (size_t)(blk * PB + pA) * 3;
    float x0 = xp[0], x1 = xp[1], x2 = xp[2];
    h2 xh0 = ph2(x0, x0), xh1 = ph2(x1, x1), xh2 = ph2(x2, x2);
    h2 tp[4], sp[4];
#pragma unroll
    for (int u2 = 0; u2 < 4; u2++) {
      h2 z = xh0 * wx2[u2] + xh1 * wy2[u2] + xh2 * wz2[u2] + bB2[u2];
      float t0 = mytanh((float)z[0]);
      float t1 = mytanh((float)z[1]);
      tp[u2] = ph2(t0, t1);
      sp[u2] = one2 - tp[u2] * tp[u2];
    }
    unsigned* sA = s_A[buf];
    const int cbase = (g ^ pA) << 2;
    uint4 q;
    q = make_uint4(bc(tp[0]), bc(tp[1]), bc(tp[2]), bc(tp[3]));
    *(uint4*)&sA[(pA)      * 64 + cbase] = q;
    q = make_uint4(bc(sp[0]*wx2[0]), bc(sp[1]*wx2[1]), bc(sp[2]*wx2[2]), bc(sp[3]*wx2[3]));
    *(uint4*)&sA[(16 + pA) * 64 + cbase] = q;
    q = make_uint4(bc(sp[0]*wy2[0]), bc(sp[1]*wy2[1]), bc(sp[2]*wy2[2]), bc(sp[3]*wy2[3]));
    *(uint4*)&sA[(32 + pA) * 64 + cbase] = q;
    q = make_uint4(bc(sp[0]*wz2[0]), bc(sp[1]*wz2[1]), bc(sp[2]*wz2[2]), bc(sp[3]*wz2[3]));
    *(uint4*)&sA[(48 + pA) * 64 + cbase] = q;
    q = make_uint4(bc((tp[0]*sp[0])*m2wq2[0]), bc((tp[1]*sp[1])*m2wq2[1]),
                   bc((tp[2]*sp[2])*m2wq2[2]), bc((tp[3]*sp[3])*m2wq2[3]));
    *(uint4*)&sA[(64 + pA) * 64 + cbase] = q;
  };

  // ---- phase D+E (waves 0,1): paired-b128 reads, residual in regs ----
  auto phaseDE = [&]() {
    const int pbase = col * 128;   // A-operand row m = point = col
    f32x4 dy = (f32x4){0.0f, 0.0f, 0.0f, 0.0f};
    f32x4 dl = (f32x4){0.0f, 0.0f, 0.0f, 0.0f};
#pragma unroll
    for (int ks = 0; ks < 4; ks++) {
      int pos = ((((ks << 2) + quad) ^ col) << 2);
      half8 afy = *(const half8*)&s_HG[pbase + pos];
      half8 afl = *(const half8*)&s_HG[pbase + 64 + pos];
      dy = __builtin_amdgcn_mfma_f32_16x16x32_f16(afy, w3f[ks], dy, 0, 0, 0);
      dl = __builtin_amdgcn_mfma_f32_16x16x32_f16(afl, w3f[ks], dl, 0, 0, 0);
    }
    if (col >= 1) {
#pragma unroll
      for (int r = 0; r < 4; r++) {
        float yv  = dy[r] + b3v;
        float res = fmaf(k2v, yv, dl[r]);
        wsum += res * res;
      }
    }
  };

  // ---- prologue ----
  phaseA(blockIdx.x, 0);
  __syncthreads();

  int parity = 0;
  bool first = true;
  for (int blk = blockIdx.x; blk < NBLK; blk += gridDim.x, parity ^= 1) {
    // D(i-1)+E(i-1): waves 0,1; reads s_HG (pre-b1 region)
    if (w < 2 && !first) phaseDE();
    first = false;

    // A(i+1): packed VALU, independent of B(i) below
    int nblk = blk + (int)gridDim.x;
    if (nblk < NBLK) phaseA(nblk, parity ^ 1);

    // B(i): [80x128]x[128x128] from s_A[parity]; wave w n-tiles 2w,2w+1
    const unsigned* sA = s_A[parity];
    f32x4 acc[5][2];
#pragma unroll
    for (int v = 0; v < 5; v++)
#pragma unroll
      for (int ntl = 0; ntl < 2; ntl++)
        acc[v][ntl] = (f32x4){0.0f, 0.0f, 0.0f, 0.0f};

#pragma unroll
    for (int v = 0; v < 5; v++) {
      const int rb = (v * 16 + col) * 64;
#pragma unroll
      for (int ks = 0; ks < 4; ks++) {
        half8 af = *(const half8*)&sA[rb + ((((ks << 2) + quad) ^ col) << 2)];
        acc[v][0] = __builtin_amdgcn_mfma_f32_16x16x32_f16(af, w2f[0][ks], acc[v][0], 0, 0, 0);
        acc[v][1] = __builtin_amdgcn_mfma_f32_16x16x32_f16(af, w2f[1][ks], acc[v][1], 0, 0, 0);
      }
    }
    __syncthreads();  // b1: D(i-1) readers done; HG free for C(i)

    // C(i): packed-f16 layer-2 elementwise -> paired writes into s_HG
#pragma unroll
    for (int r = 0; r < 4; r++) {
      int p = (quad << 2) + r;
      float t0 = mytanh(acc[0][0][r] + b2r0);
      float t1 = mytanh(acc[0][1][r] + b2r1);
      h2 tp = ph2(t0, t1);
      h2 sp = one2 - tp * tp;
      h2 d0 = ph2(acc[1][0][r], acc[1][1][r]);
      h2 d1 = ph2(acc[2][0][r], acc[2][1][r]);
      h2 d2 = ph2(acc[3][0][r], acc[3][1][r]);
      h2 Ap = ph2(acc[4][0][r], acc[4][1][r]);
      h2 Bp = d0 * d0 + d1 * d1 + d2 * d2;
      h2 gg = sp * (Ap + m2c * (tp * Bp));
      int q   = 16 * w + col;
      int pos = (((q >> 2) ^ p) << 2) + (q & 3);
      s_HG[p * 128 + pos]      = bc(tp);
      s_HG[p * 128 + 64 + pos] = bc(gg);
    }
    __syncthreads();  // b2: HG ready for D(i)
  }

  // epilogue: D+E for the final pass
  if (w < 2) phaseDE();

  // ---- final: wave reduce, one atomic per wave ----
#pragma unroll
  for (int off = 32; off > 0; off >>= 1)
    wsum += __shfl_down(wsum, off, 64);
  if (l == 0)
    atomicAdd(out, wsum * (1.0f / ((float)NPTS * (float)(FCH - 1))));
}

extern "C" void kernel_launch(void* const* d_in, const int* in_sizes, int n_in,
                              void* d_out, int out_size, void* d_ws, size_t ws_size,
                              hipStream_t stream) {
  const float* x     = (const float*)d_in[0];
  const float* omega = (const float*)d_in[1];
  const float* W1    = (const float*)d_in[2];
  const float* b1    = (const float*)d_in[3];
  const float* W2    = (const float*)d_in[4];
  const float* b2    = (const float*)d_in[5];
  const float* W3    = (const float*)d_in[6];
  const float* b3    = (const float*)d_in[7];
  float* out = (float*)d_out;

  (void)hipMemsetAsync(out, 0, sizeof(float), stream);
  helmholtz_kernel<<<GRID, BLOCK, 0, stream>>>(x, omega, W1, b1, W2, b2, W3, b3, out);
}